// Round 1
// baseline (125.344 us; speedup 1.0000x reference)
//
#include <hip/hip_runtime.h>

// SecurePooling: x (32,1000,14,14) f32 -> pred (32,) int32
// H=W=14, K=6, ST=2, xs={0,2,4,6,8}, M=5.
// All window/overlap sums are 4-corner lookups in the even-coordinate SAT
// S[r][c] = sum(x[0:2r, 0:2c]), r,c in 0..7.  total = S[7][7].
// w(i,j)   = S[i+3][j+3]-S[i][j+3]-S[i+3][j]+S[i][j]
// overlap rows for (i1,j1): rlo=max, rhi=max(min+3, rlo) (empty cancels exactly).

#define NC 1000
#define NBC 32000   // 32*1000

// ---------------- Kernel A: per-(b,c) even SAT ----------------
__global__ __launch_bounds__(64) void satA(const float* __restrict__ x,
                                           float* __restrict__ Sws) {
    const int bc = blockIdx.x * 64 + threadIdx.x;        // 0..31999 (grid exact)
    const float4* p = reinterpret_cast<const float4*>(x + (size_t)bc * 196);

    float S[8][8];
#pragma unroll
    for (int c = 0; c < 8; ++c) S[0][c] = 0.f;
    float colacc[7];
#pragma unroll
    for (int c = 0; c < 7; ++c) colacc[c] = 0.f;

#pragma unroll
    for (int r = 0; r < 7; ++r) {                        // row-pair r: rows 2r,2r+1
        float rowf[28];
#pragma unroll
        for (int i = 0; i < 7; ++i) {
            float4 v = p[r * 7 + i];
            rowf[4 * i + 0] = v.x; rowf[4 * i + 1] = v.y;
            rowf[4 * i + 2] = v.z; rowf[4 * i + 3] = v.w;
        }
        S[r + 1][0] = 0.f;
        float run = 0.f;
#pragma unroll
        for (int c = 0; c < 7; ++c) {
            float blk = rowf[2 * c] + rowf[2 * c + 1] + rowf[14 + 2 * c] + rowf[14 + 2 * c + 1];
            colacc[c] += blk;
            run += colacc[c];
            S[r + 1][c + 1] = run;
        }
    }
#pragma unroll
    for (int k = 0; k < 64; ++k)
        Sws[(size_t)k * NBC + bc] = S[k >> 3][k & 7];
}

// ---------------- Kernel B: per (b,i1,i2) argmax streams ----------------
#define WSUM(i, j) (S[((i)+3)*8+((j)+3)] - S[(i)*8+((j)+3)] - S[((i)+3)*8+(j)] + S[(i)*8+(j)])

template <int I1, int I2>
__device__ __forceinline__ void processB(const float* __restrict__ Sws, int b,
                                         int* __restrict__ p1_arr,
                                         int* __restrict__ agree_arr, int t,
                                         float* __restrict__ lv, int* __restrict__ li) {
    const int tid = threadIdx.x;
    float bval[26];
    int bidx[26];
#pragma unroll
    for (int s = 0; s < 26; ++s) { bval[s] = -3.4e38f; bidx[s] = 0x7fffffff; }

    const int base = b * NC;
    for (int c = tid; c < NC; c += 256) {
        float S[64];
#pragma unroll
        for (int k = 0; k < 64; ++k)
            S[k] = Sws[k * NBC + base + c];
        const float total = S[63];
        const float lt = total - WSUM(I1, I2);           // one_mask logit
        if (lt > bval[0]) { bval[0] = lt; bidx[0] = c; } // first-max within thread
#pragma unroll
        for (int j1 = 0; j1 < 5; ++j1) {
#pragma unroll
            for (int j2 = 0; j2 < 5; ++j2) {
                const int rlo = (I1 > j1 ? I1 : j1);
                const int rmn = (I1 < j1 ? I1 : j1);
                const int rhi = (rmn + 3 > rlo ? rmn + 3 : rlo);
                const int clo = (I2 > j2 ? I2 : j2);
                const int cmn = (I2 < j2 ? I2 : j2);
                const int chi = (cmn + 3 > clo ? cmn + 3 : clo);
                float rect = S[rhi * 8 + chi] - S[rlo * 8 + chi]
                           - S[rhi * 8 + clo] + S[rlo * 8 + clo];
                float v = lt - WSUM(j1, j2) + rect;
                const int s = 1 + j1 * 5 + j2;
                if (v > bval[s]) { bval[s] = v; bidx[s] = c; }
            }
        }
    }

    // wave butterfly reduce, lexicographic (val desc, idx asc)
#pragma unroll
    for (int s = 0; s < 26; ++s) {
#pragma unroll
        for (int off = 1; off < 64; off <<= 1) {
            float ov = __shfl_xor(bval[s], off, 64);
            int oi = __shfl_xor(bidx[s], off, 64);
            if (ov > bval[s] || (ov == bval[s] && oi < bidx[s])) { bval[s] = ov; bidx[s] = oi; }
        }
    }
    const int wave = tid >> 6, lane = tid & 63;
    if (lane == 0) {
#pragma unroll
        for (int s = 0; s < 26; ++s) { lv[wave * 26 + s] = bval[s]; li[wave * 26 + s] = bidx[s]; }
    }
    __syncthreads();
    if (tid == 0) {
        int fin[26];
#pragma unroll
        for (int s = 0; s < 26; ++s) {
            float v = lv[s]; int i = li[s];
            for (int w = 1; w < 4; ++w) {
                float ov = lv[w * 26 + s]; int oi = li[w * 26 + s];
                if (ov > v || (ov == v && oi < i)) { v = ov; i = oi; }
            }
            fin[s] = i;
        }
        const int p1 = fin[0];
        int agree = 1;
#pragma unroll
        for (int s = 1; s < 26; ++s) agree &= (fin[s] == p1);
        p1_arr[b * 25 + t] = p1;
        agree_arr[b * 25 + t] = agree;
    }
}

__global__ __launch_bounds__(256) void kernB(const float* __restrict__ Sws,
                                             int* __restrict__ p1_arr,
                                             int* __restrict__ agree_arr) {
    __shared__ float lv[4 * 26];
    __shared__ int li[4 * 26];
    const int blk = blockIdx.x;
    const int b = blk / 25;
    const int t = blk % 25;
#define CASE_B(T) case T: processB<(T) / 5, (T) % 5>(Sws, b, p1_arr, agree_arr, t, lv, li); break;
    switch (t) {
        CASE_B(0)  CASE_B(1)  CASE_B(2)  CASE_B(3)  CASE_B(4)
        CASE_B(5)  CASE_B(6)  CASE_B(7)  CASE_B(8)  CASE_B(9)
        CASE_B(10) CASE_B(11) CASE_B(12) CASE_B(13) CASE_B(14)
        CASE_B(15) CASE_B(16) CASE_B(17) CASE_B(18) CASE_B(19)
        CASE_B(20) CASE_B(21) CASE_B(22) CASE_B(23) CASE_B(24)
    }
#undef CASE_B
}

// ---------------- Kernel C: per-b final decision ----------------
__global__ __launch_bounds__(256) void kernC(const float* __restrict__ Sws,
                                             const int* __restrict__ p1_arr,
                                             const int* __restrict__ agree_arr,
                                             int* __restrict__ out) {
    const int b = blockIdx.x;
    const int tid = threadIdx.x;
    float bv = -3.4e38f; int bi = 0x7fffffff;
    for (int c = tid; c < NC; c += 256) {
        float t = Sws[63 * NBC + b * NC + c];            // total
        if (t > bv) { bv = t; bi = c; }
    }
#pragma unroll
    for (int off = 1; off < 64; off <<= 1) {
        float ov = __shfl_xor(bv, off, 64);
        int oi = __shfl_xor(bi, off, 64);
        if (ov > bv || (ov == bv && oi < bi)) { bv = ov; bi = oi; }
    }
    __shared__ float lv[4];
    __shared__ int li[4];
    const int wave = tid >> 6, lane = tid & 63;
    if (lane == 0) { lv[wave] = bv; li[wave] = bi; }
    __syncthreads();
    if (tid == 0) {
        float v = lv[0]; int pred = li[0];
        for (int w = 1; w < 4; ++w)
            if (lv[w] > v || (lv[w] == v && li[w] < pred)) { v = lv[w]; pred = li[w]; }
        int ans = pred;
        for (int t = 0; t < 25; ++t) {
            int p1 = p1_arr[b * 25 + t];
            if (agree_arr[b * 25 + t] && p1 != pred) { ans = p1; break; }
        }
        out[b] = ans;
    }
}

extern "C" void kernel_launch(void* const* d_in, const int* in_sizes, int n_in,
                              void* d_out, int out_size, void* d_ws, size_t ws_size,
                              hipStream_t stream) {
    const float* x = (const float*)d_in[0];
    int* out = (int*)d_out;

    float* Sws = (float*)d_ws;                           // 64*32000 f32 = 8.192 MB
    int* p1_arr = (int*)((char*)d_ws + (size_t)64 * NBC * 4);   // 800 ints
    int* agree_arr = p1_arr + 32 * 25;                   // 800 ints

    satA<<<NBC / 64, 64, 0, stream>>>(x, Sws);
    kernB<<<32 * 25, 256, 0, stream>>>(Sws, p1_arr, agree_arr);
    kernC<<<32, 256, 0, stream>>>(Sws, p1_arr, agree_arr, out);
}

// Round 2
// 103.660 us; speedup vs baseline: 1.2092x; 1.2092x over previous
//
#include <hip/hip_runtime.h>

// SecurePooling: x (32,1000,14,14) f32 -> pred (32,) int32
// Even-coordinate SAT S[r][c] = sum(x[0:2r,0:2c]), r,c in 0..7 is a complete
// sufficient statistic (windows at 0,2,4,6,8 with K=6, ST=2).
// two[i][j] == two[j][i] and two[i][i] == one_mask[i]  ->  351 streams per b:
//   325 unordered pairs + 25 one-mask + 1 total.

#define NC 1000
#define NBC 32000      // 32*1000
#define CHUNKS 4
#define CLEN 250       // NC / CHUNKS
#define NG 14          // 13 pair-groups of 25 + 1 group {25 one-mask, total}
#define MAXST 26

__host__ __device__ constexpr int tri_off(int p) { return p * 25 - p * (p - 1) / 2; }

__device__ __forceinline__ unsigned fkey(float v) {
    unsigned u = __float_as_uint(v);
    return u ^ (unsigned)(((int)u >> 31) | 0x80000000);
}

// ---------------- Kernel A: per-(b,c) even SAT, LDS-staged coalesced ----------------
__global__ __launch_bounds__(256) void satA(const float* __restrict__ x,
                                            float* __restrict__ Sws) {
    __shared__ float lx[64 * 197];                       // 197: odd stride, conflict-free
    const int tid = threadIdx.x;
    const int blk = blockIdx.x;                          // 500 blocks x 64 images
    const float4* x4 = reinterpret_cast<const float4*>(x) + (size_t)blk * 3136;
#pragma unroll
    for (int it = 0; it < 13; ++it) {
        int f = it * 256 + tid;                          // 3136 float4 per block
        if (f < 3136) {
            float4 v = x4[f];
            int img = f / 49;                            // 49 float4 per image
            int off = f - img * 49;
            float* d = &lx[img * 197 + off * 4];
            d[0] = v.x; d[1] = v.y; d[2] = v.z; d[3] = v.w;
        }
    }
    __syncthreads();
    if (tid < 64) {
        const float* im = &lx[tid * 197];
        float S[8][8];
#pragma unroll
        for (int c = 0; c < 8; ++c) S[0][c] = 0.f;
        float colacc[7];
#pragma unroll
        for (int c = 0; c < 7; ++c) colacc[c] = 0.f;
#pragma unroll
        for (int r = 0; r < 7; ++r) {                    // rows 2r,2r+1 = 28 contiguous
            float rowf[28];
#pragma unroll
            for (int j = 0; j < 28; ++j) rowf[j] = im[r * 28 + j];
            S[r + 1][0] = 0.f;
            float run = 0.f;
#pragma unroll
            for (int c = 0; c < 7; ++c) {
                float blk2 = rowf[2 * c] + rowf[2 * c + 1] + rowf[14 + 2 * c] + rowf[14 + 2 * c + 1];
                colacc[c] += blk2;
                run += colacc[c];
                S[r + 1][c + 1] = run;
            }
        }
        const int bc = blk * 64 + tid;
#pragma unroll
        for (int k = 0; k < 64; ++k)
            Sws[(size_t)k * NBC + bc] = S[k >> 3][k & 7];
    }
}

// ---------------- Kernel B: symmetric streams, LDS segment-reduce ----------------
#define WSUM(i, j) (S[((i)+3)*8+((j)+3)] - S[(i)*8+((j)+3)] - S[((i)+3)*8+(j)] + S[(i)*8+(j)])

template <int G>
__device__ __forceinline__ void procB(const float* __restrict__ Sws, int b, int chunk,
                                      unsigned long long* __restrict__ part,
                                      unsigned* __restrict__ kv, unsigned* __restrict__ kc) {
    const int tid = threadIdx.x;
    const int c = chunk * CLEN + tid;
    const bool act = (tid < CLEN);

    float S[64];
    if (act) {
        const int base = b * NC + c;
#pragma unroll
        for (int k = 0; k < 64; ++k) S[k] = Sws[k * NBC + base];
    } else {
#pragma unroll
        for (int k = 0; k < 64; ++k) S[k] = 0.f;
    }
    const float total = S[63];
    constexpr int NST = (G == 13) ? 26 : 25;

#pragma unroll
    for (int ph = 0; ph < 2; ++ph) {
        const int lo = ph * 13;
        const int cnt = (NST - lo) < 13 ? (NST - lo) : 13;
        // --- compute this phase's stream keys into LDS (row stride 13: bank-free) ---
        if (act) {
#pragma unroll
            for (int i = 0; i < 13; ++i) {
                const int sl = lo + i;
                if (sl < NST) {
                    float v;
                    if constexpr (G == 13) {
                        v = (sl < 25) ? (total - WSUM(sl / 5, sl % 5)) : total;
                    } else {
                        const int pid = G * 25 + sl;
                        int p = 0;
                        while (tri_off(p + 1) <= pid) ++p;      // folds after unroll
                        const int q = p + (pid - tri_off(p));
                        const int p1 = p / 5, p2 = p % 5, q1 = q / 5, q2 = q % 5;
                        const int rlo = (p1 > q1 ? p1 : q1);
                        const int rmn = (p1 < q1 ? p1 : q1);
                        const int rhi = (rmn + 3 > rlo ? rmn + 3 : rlo);
                        const int clo = (p2 > q2 ? p2 : q2);
                        const int cmn = (p2 < q2 ? p2 : q2);
                        const int chi = (cmn + 3 > clo ? cmn + 3 : clo);
                        const float rect = S[rhi * 8 + chi] - S[rlo * 8 + chi]
                                         - S[rhi * 8 + clo] + S[rlo * 8 + clo];
                        v = ((total - WSUM(p1, p2)) - WSUM(q1, q2)) + rect;
                    }
                    kv[tid * 13 + i] = fkey(v);
                    kc[tid * 13 + i] = ~(unsigned)c;            // bigger = smaller c
                }
            }
        } else {
#pragma unroll
            for (int i = 0; i < 13; ++i) { kv[tid * 13 + i] = 0u; kc[tid * 13 + i] = 0u; }
        }
        __syncthreads();
        // --- reduce: thread (s,seg), s<cnt, seg<16: 16 serial + 4-step butterfly ---
        if (tid < 208) {
            const int s = tid >> 4, seg = tid & 15;
            if (s < cnt) {
                unsigned bk = 0u, bc2 = 0u;
#pragma unroll
                for (int i = 0; i < 16; ++i) {
                    const int row = seg * 16 + i;
                    unsigned k2 = kv[row * 13 + s], c2 = kc[row * 13 + s];
                    if (k2 > bk || (k2 == bk && c2 > bc2)) { bk = k2; bc2 = c2; }
                }
#pragma unroll
                for (int off = 1; off < 16; off <<= 1) {
                    unsigned ok = __shfl_xor(bk, off, 16);
                    unsigned oc = __shfl_xor(bc2, off, 16);
                    if (ok > bk || (ok == bk && oc > bc2)) { bk = ok; bc2 = oc; }
                }
                if (seg == 0)
                    part[((b * NG + G) * CHUNKS + chunk) * MAXST + lo + s] =
                        ((unsigned long long)bk << 32) | bc2;
            }
        }
        __syncthreads();
    }
}

__global__ __launch_bounds__(256) void kernB(const float* __restrict__ Sws,
                                             unsigned long long* __restrict__ part) {
    __shared__ unsigned kv[256 * 13];
    __shared__ unsigned kc[256 * 13];
    const int b = blockIdx.x / 56;                      // 14 groups * 4 chunks
    const int r = blockIdx.x % 56;
    const int g = r >> 2;
    const int chunk = r & 3;
#define CASE_G(T) case T: procB<T>(Sws, b, chunk, part, kv, kc); break;
    switch (g) {
        CASE_G(0) CASE_G(1) CASE_G(2) CASE_G(3) CASE_G(4) CASE_G(5) CASE_G(6)
        CASE_G(7) CASE_G(8) CASE_G(9) CASE_G(10) CASE_G(11) CASE_G(12) CASE_G(13)
    }
#undef CASE_G
}

// ---------------- Kernel C: merge chunks + final decision ----------------
__global__ __launch_bounds__(64) void kernC(const unsigned long long* __restrict__ part,
                                            int* __restrict__ out) {
    const int b = blockIdx.x;
    const int t = threadIdx.x;
    auto mrg = [&](int g, int s) {
        unsigned long long m = 0ull;
#pragma unroll
        for (int ch = 0; ch < CHUNKS; ++ch) {
            unsigned long long v = part[((b * NG + g) * CHUNKS + ch) * MAXST + s];
            if (v > m) m = v;
        }
        return m;
    };
    const unsigned long long predk = mrg(13, 25);
    const int pred = (int)(~(unsigned)predk);

    int p1 = 0;
    bool ag = false;
    if (t < 25) {
        const unsigned long long p1k = mrg(13, t);
        const unsigned p1idx = (unsigned)p1k;
        p1 = (int)(~p1idx);
        ag = true;
        for (int j = 0; j < 25; ++j) {
            const int a = t < j ? t : j;
            const int bb = t < j ? j : t;
            const int pid = tri_off(a) + (bb - a);
            const unsigned long long fk = mrg(pid / 25, pid % 25);
            ag = ag && ((unsigned)fk == p1idx);
        }
    }
    const bool cand = (t < 25) && ag && (p1 != pred);
    const unsigned long long mask = __ballot(cand);
    int ans = pred;
    if (mask) {
        const int first = __ffsll((unsigned long long)mask) - 1;
        ans = __shfl(p1, first, 64);
    }
    if (t == 0) out[b] = ans;
}

extern "C" void kernel_launch(void* const* d_in, const int* in_sizes, int n_in,
                              void* d_out, int out_size, void* d_ws, size_t ws_size,
                              hipStream_t stream) {
    const float* x = (const float*)d_in[0];
    int* out = (int*)d_out;

    float* Sws = (float*)d_ws;                                   // 64*32000*4 = 8.192 MB
    unsigned long long* part =
        (unsigned long long*)((char*)d_ws + (size_t)64 * NBC * 4); // 32*14*4*26*8 = 373 KB

    satA<<<NBC / 64, 256, 0, stream>>>(x, Sws);
    kernB<<<32 * NG * CHUNKS, 256, 0, stream>>>(Sws, part);
    kernC<<<32, 64, 0, stream>>>(part, out);
}